// Round 5
// baseline (1239.683 us; speedup 1.0000x reference)
//
#include <hip/hip_runtime.h>
#include <hip/hip_bf16.h>
#include <math.h>

#define B_ 128
#define L_ 128
#define N_ 6
#define FA_ 39
#define FB_ 10
#define D_ 200
#define MB_ 256
#define R_ 3
#define T_ 2
#define NEGV -9e8f
#define BL_ (B_*L_)        // 16384
#define BLD_ (BL_*D_)      // 3276800
#define G3D_ (3*D_)        // 600
#define FP32TAG 0x3F800000u
#define CTXA 16            // atoms per block in k_ctxgemm

typedef __hip_bfloat16 bf16;

__device__ __forceinline__ float b2f(const bf16 x){ return __bfloat162float(x); }
__device__ __forceinline__ float lreluf(float x){ return x>=0.f ? x : 0.01f*x; }
__device__ __forceinline__ float eluf(float x){ return x>0.f ? x : expm1f(x); }
__device__ __forceinline__ float sigmf(float x){ return 1.f/(1.f+expf(-x)); }

#define NSEG 25
struct CvtArgs { const void* src[NSEG]; int ofs[NSEG+1]; };

// canonicalize all float inputs (bf16 OR fp32 storage) to fp32 in ws
__global__ void k_convert(CvtArgs c, float* __restrict__ dst, const unsigned* __restrict__ amtag, int total){
    int i = blockIdx.x*blockDim.x + threadIdx.x;
    if (i >= total) return;
    bool f32 = (*amtag == FP32TAG);
    int s = 0;
    while (i >= c.ofs[s+1]) s++;
    int j = i - c.ofs[s];
    dst[i] = f32 ? ((const float*)c.src[s])[j] : b2f(((const bf16*)c.src[s])[j]);
}

// transpose GRU weights to [r][k][j] fp32 for coalesced gate-GEMM loads (dual-dtype read)
__global__ void k_transpose(const void* __restrict__ Wih, const void* __restrict__ Whh,
                            float* __restrict__ Ti, float* __restrict__ Th,
                            const unsigned* __restrict__ amtag){
    int idx = blockIdx.x*blockDim.x + threadIdx.x;
    if (idx >= R_*D_*G3D_) return;       // 360000
    bool f32 = (*amtag == FP32TAG);
    int j  = idx % G3D_;
    int rk = idx / G3D_;
    int k  = rk % D_;
    int r  = rk / D_;
    size_t si = ((size_t)r*G3D_ + j)*D_ + k;
    Ti[idx] = f32 ? ((const float*)Wih)[si] : b2f(((const bf16*)Wih)[si]);
    Th[idx] = f32 ? ((const float*)Whh)[si] : b2f(((const bf16*)Whh)[si]);
}

// atom_feature = lrelu(atom_list @ W_atom + b_atom); h = cur = atom_feature
__global__ void k_atomfeat(const float* __restrict__ atom_list, const float* __restrict__ W_atom,
                           const float* __restrict__ b_atom, float* __restrict__ h, float* __restrict__ cur){
    int idx = blockIdx.x*blockDim.x + threadIdx.x;
    if (idx >= BLD_) return;
    int d = idx % D_;
    int al = idx / D_;
    const float* arow = atom_list + (size_t)al*FA_;
    float acc = b_atom[d];
    for (int k=0;k<FA_;k++) acc += arow[k] * W_atom[k*D_ + d];
    float v = lreluf(acc);
    h[idx] = v; cur[idx] = v;
}

// P = atom_list @ W_nei[0:FA] + b_nei  (atom half of round-0 neighbor features, pre-lrelu)
__global__ void k_precompP(const float* __restrict__ atom_list, const float* __restrict__ W_nei,
                           const float* __restrict__ b_nei, float* __restrict__ P){
    int idx = blockIdx.x*blockDim.x + threadIdx.x;
    if (idx >= BLD_) return;
    int d = idx % D_;
    int al = idx / D_;
    const float* arow = atom_list + (size_t)al*FA_;
    float acc = b_nei[d];
    for (int k=0;k<FA_;k++) acc += arow[k] * W_nei[k*D_ + d];
    P[idx] = acc;
}

// per-atom dots with W_align[r]: s1 = cur . Wa[0:D], tb = cur . Wa[D:2D]
__global__ void k_dots(const float* __restrict__ cur, const float* __restrict__ W_align, int r,
                       float* __restrict__ s1, float* __restrict__ tb){
    int wave = (blockIdx.x*blockDim.x + threadIdx.x) >> 6;
    int lane = threadIdx.x & 63;
    if (wave >= BL_) return;
    const float* Wa = W_align + r*2*D_;
    const float* row = cur + (size_t)wave*D_;
    float a1 = 0.f, a2 = 0.f;
    for (int k=lane; k<D_; k+=64){
        float c = row[k];
        a1 += c * Wa[k];
        a2 += c * Wa[D_+k];
    }
    for (int o=32;o>0;o>>=1){ a1 += __shfl_xor(a1,o); a2 += __shfl_xor(a2,o); }
    if (lane==0){ s1[wave]=a1; tb[wave]=a2; }
}

// attention: softmax + weighted neighbor sum. 4 atoms per 256-thread block, one wave per atom.
// r==0: neighbor features = lrelu(P[atom] + bond_row @ W_nei[FA:]) built in LDS on the fly.
__global__ void __launch_bounds__(256) k_attn(
        const float* __restrict__ cur, const float* __restrict__ s1, const float* __restrict__ tb,
        const int* __restrict__ adl, const int* __restrict__ bdl,
        const float* __restrict__ P, const float* __restrict__ bond_list,
        const float* __restrict__ W_nei,
        const float* __restrict__ W_align, const float* __restrict__ b_align, int r,
        float* __restrict__ wnei, float* __restrict__ wsum){
    int wv = threadIdx.x >> 6;
    int lane = threadIdx.x & 63;
    int al = blockIdx.x*4 + wv;
    int bi = al >> 7;            // / L_
    __shared__ float s_nei[4][N_][D_];

    int idxn[N_]; bool pad[N_];
    for (int n=0;n<N_;n++){ idxn[n] = adl[al*N_ + n]; pad[n] = (idxn[n] == L_-1); }

    float s2[N_];
    if (r == 0){
        const float* Wb = W_nei + FA_*D_;   // bond half, 10x200, L1-resident
        for (int j = lane; j < N_*D_; j += 64){
            int n = j / D_, d = j - n*D_;
            int bd = bdl[al*N_ + n];
            const float* brow = bond_list + ((size_t)bi*MB_ + bd)*FB_;
            float acc = P[((size_t)bi*L_ + idxn[n])*D_ + d];
            #pragma unroll
            for (int k=0;k<FB_;k++) acc += brow[k] * Wb[k*D_ + d];
            s_nei[wv][n][d] = lreluf(acc);
        }
        const float* Wab = W_align + D_;   // bottom half of W_align[0]
        for (int n=0;n<N_;n++){
            float acc = 0.f;
            for (int d=lane; d<D_; d+=64) acc += s_nei[wv][n][d] * Wab[d];
            for (int o=32;o>0;o>>=1) acc += __shfl_xor(acc,o);
            s2[n] = acc;                   // butterfly leaves sum in all lanes
        }
    } else {
        float tmp = 0.f;
        if (lane < N_) tmp = tb[bi*L_ + idxn[lane]];
        for (int n=0;n<N_;n++) s2[n] = __shfl(tmp, n);
    }

    float s1v = s1[al];
    float bav = b_align[r];
    float a[N_]; float mx = -1e30f;
    for (int n=0;n<N_;n++){
        float v = lreluf(s1v + s2[n] + bav);
        if (pad[n]) v += NEGV;
        a[n] = v; mx = fmaxf(mx, v);
    }
    float w[N_]; float se = 0.f;
    for (int n=0;n<N_;n++){ float e = expf(a[n]-mx); w[n]=e; se += e; }
    float inv = 1.f/se; float wsv = 0.f;
    for (int n=0;n<N_;n++){ w[n] = pad[n] ? 0.f : w[n]*inv; wsv += w[n]; }

    if (r == 0){
        for (int d=lane; d<D_; d+=64){
            float acc = 0.f;
            #pragma unroll
            for (int n=0;n<N_;n++) acc += w[n] * s_nei[wv][n][d];
            wnei[(size_t)al*D_ + d] = acc;
        }
    } else {
        for (int d=lane; d<D_; d+=64){
            float acc = 0.f;
            #pragma unroll
            for (int n=0;n<N_;n++) acc += w[n] * cur[((size_t)bi*L_ + idxn[n])*D_ + d];
            wnei[(size_t)al*D_ + d] = acc;
        }
    }
    if (lane==0) wsum[al] = wsv;
}

// ctx = elu(wnei @ W_attend[r] + wsum * b_attend[r]) — CTXA atom rows, float4 LDS k-unroll
__global__ void __launch_bounds__(256) k_ctxgemm(const float* __restrict__ wnei,
        const float* __restrict__ wsum,
        const float* __restrict__ W_attend, const float* __restrict__ b_attend, int r,
        float* __restrict__ ctx){
    int tid = threadIdx.x;
    int al0 = blockIdx.x * CTXA;
    __shared__ float s_x[CTXA][D_];
    __shared__ float s_ws[CTXA];
    for (int i = tid; i < CTXA*D_; i += 256){
        int a = i / D_, d = i - a*D_;
        s_x[a][d] = wnei[(size_t)(al0+a)*D_ + d];
    }
    if (tid < CTXA) s_ws[tid] = wsum[al0 + tid];
    __syncthreads();
    int j = tid;
    if (j < D_){
        const float* W = W_attend + (size_t)r*D_*D_;
        float bv = b_attend[r*D_ + j];
        float acc[CTXA];
        #pragma unroll
        for (int a=0;a<CTXA;a++) acc[a] = 0.f;
        for (int k=0;k<D_;k+=4){
            float w0 = W[k*D_ + j], w1 = W[(k+1)*D_ + j];
            float w2 = W[(k+2)*D_ + j], w3 = W[(k+3)*D_ + j];
            #pragma unroll
            for (int a=0;a<CTXA;a++){
                float4 xv = *(const float4*)&s_x[a][k];
                acc[a] += xv.x*w0 + xv.y*w1 + xv.z*w2 + xv.w*w3;
            }
        }
        #pragma unroll
        for (int a=0;a<CTXA;a++)
            ctx[(size_t)(al0+a)*D_ + j] = eluf(acc[a] + s_ws[a]*bv);
    }
}

// fused GRU: register-blocked gates GEMM + in-register combine. 8 atoms per block;
// thread d owns all 6 gate dot-products for 8 atoms (48 fp32 accumulators).
__global__ void __launch_bounds__(256) k_gruf(const float* __restrict__ ctx, float* __restrict__ h,
        float* __restrict__ cur,
        const float* __restrict__ Ti, const float* __restrict__ Th,
        const float* __restrict__ bih, const float* __restrict__ bhh, int r){
    int tid = threadIdx.x;
    int al0 = blockIdx.x * 8;
    __shared__ float s_x[8][D_], s_h[8][D_];
    for (int i = tid; i < 8*D_; i += 256){
        int a = i / D_, d = i - a*D_;
        s_x[a][d] = ctx[(size_t)(al0+a)*D_ + d];
        s_h[a][d] = h[(size_t)(al0+a)*D_ + d];
    }
    __syncthreads();
    int d = tid;
    if (d < D_){
        const float* ti = Ti + (size_t)r*D_*G3D_;
        const float* th = Th + (size_t)r*D_*G3D_;
        float air[8],aiz[8],ain[8],ahr[8],ahz[8],ahn[8];
        #pragma unroll
        for (int a=0;a<8;a++){ air[a]=0;aiz[a]=0;ain[a]=0;ahr[a]=0;ahz[a]=0;ahn[a]=0; }
        for (int k=0;k<D_;k+=2){
            const float* t0 = ti + (size_t)k*G3D_ + d;
            const float* t1 = ti + (size_t)(k+1)*G3D_ + d;
            const float* u0 = th + (size_t)k*G3D_ + d;
            const float* u1 = th + (size_t)(k+1)*G3D_ + d;
            float wir0=t0[0], wiz0=t0[D_], win0=t0[2*D_];
            float wir1=t1[0], wiz1=t1[D_], win1=t1[2*D_];
            float whr0=u0[0], whz0=u0[D_], whn0=u0[2*D_];
            float whr1=u1[0], whz1=u1[D_], whn1=u1[2*D_];
            #pragma unroll
            for (int a=0;a<8;a++){
                float2 xv = *(const float2*)&s_x[a][k];
                float2 hv = *(const float2*)&s_h[a][k];
                air[a] += xv.x*wir0 + xv.y*wir1;
                aiz[a] += xv.x*wiz0 + xv.y*wiz1;
                ain[a] += xv.x*win0 + xv.y*win1;
                ahr[a] += hv.x*whr0 + hv.y*whr1;
                ahz[a] += hv.x*whz0 + hv.y*whz1;
                ahn[a] += hv.x*whn0 + hv.y*whn1;
            }
        }
        float bir=bih[r*G3D_+d], biz=bih[r*G3D_+D_+d], bin=bih[r*G3D_+2*D_+d];
        float bhr=bhh[r*G3D_+d], bhz=bhh[r*G3D_+D_+d], bhn=bhh[r*G3D_+2*D_+d];
        #pragma unroll
        for (int a=0;a<8;a++){
            float rr = sigmf(air[a]+bir + ahr[a]+bhr);
            float zz = sigmf(aiz[a]+biz + ahz[a]+bhz);
            float nn = tanhf(ain[a]+bin + rr*(ahn[a]+bhn));
            float hv = s_h[a][d];
            float hn = (1.f-zz)*nn + zz*hv;
            h[(size_t)(al0+a)*D_+d] = hn;
            cur[(size_t)(al0+a)*D_+d] = fmaxf(hn, 0.f);
        }
    }
}

__device__ __forceinline__ float blockReduceSum(float v, float* s_red){
    for (int o=32;o>0;o>>=1) v += __shfl_xor(v,o);
    int lane = threadIdx.x & 63, wid = threadIdx.x >> 6;
    __syncthreads();
    if (lane==0) s_red[wid] = v;
    __syncthreads();
    float r = s_red[0];
    int nw = blockDim.x >> 6;
    for (int i=1;i<nw;i++) r += s_red[i];
    return r;
}

// molecule phase: pooling, T mol-attention+GRU steps, output head. One block per molecule.
__global__ void __launch_bounds__(256) k_mol(const float* __restrict__ cur, const float* __restrict__ atom_mask,
    const float* __restrict__ Wma, const float* __restrict__ bma,
    const float* __restrict__ Wmt, const float* __restrict__ bmt,
    const float* __restrict__ mWih, const float* __restrict__ mWhh,
    const float* __restrict__ mbih, const float* __restrict__ mbhh,
    const float* __restrict__ Wme, const float* __restrict__ bme,
    const float* __restrict__ Wout, const float* __restrict__ bout,
    void* __restrict__ out, const unsigned* __restrict__ amtag){
    int b = blockIdx.x, tid = threadIdx.x;
    __shared__ float s_am[L_], s_neg[L_], s_mf[D_], s_act[D_], s_sc[L_], s_w[L_];
    __shared__ float s_wc[D_], s_ctx[D_], s_gi[G3D_], s_gh[G3D_], s_red[8];
    const float* curb = cur + (size_t)b*L_*D_;
    if (tid < L_){
        float am = atom_mask[b*L_ + tid];
        s_am[tid] = am;
        s_neg[tid] = (am == 0.f) ? NEGV : 0.f;
    }
    __syncthreads();
    for (int d=tid; d<D_; d+=256){
        float acc = 0.f;
        for (int l=0;l<L_;l++) acc += curb[l*D_ + d] * s_am[l];
        s_mf[d] = acc; s_act[d] = fmaxf(acc, 0.f);
    }
    __syncthreads();
    for (int t=0;t<T_;t++){
        float p = 0.f;
        for (int d=tid; d<D_; d+=256) p += s_act[d] * Wma[d];
        float s1 = blockReduceSum(p, s_red);
        if (tid < L_){
            const float* row = curb + tid*D_;
            float sc = 0.f;
            for (int d=0; d<D_; d++) sc += row[d] * Wma[D_+d];
            sc = lreluf(s1 + sc + bma[0]);
            s_sc[tid] = sc + s_neg[tid];
        }
        __syncthreads();
        if (tid==0){ float mx=-1e30f; for (int l=0;l<L_;l++) mx=fmaxf(mx,s_sc[l]); s_red[4]=mx; }
        __syncthreads();
        if (tid < L_) s_w[tid] = expf(s_sc[tid] - s_red[4]);
        __syncthreads();
        if (tid==0){ float sm=0.f; for (int l=0;l<L_;l++) sm+=s_w[l]; s_red[5]=sm; }
        __syncthreads();
        if (tid < L_) s_w[tid] = s_w[tid]/s_red[5]*s_am[tid];
        __syncthreads();
        if (tid==0){ float sm=0.f; for (int l=0;l<L_;l++) sm+=s_w[l]; s_red[6]=sm; }
        __syncthreads();
        for (int d=tid; d<D_; d+=256){
            float acc = 0.f;
            for (int l=0;l<L_;l++) acc += s_w[l]*curb[l*D_ + d];
            s_wc[d] = acc;
        }
        __syncthreads();
        float wsm = s_red[6];
        for (int d=tid; d<D_; d+=256){
            float acc = wsm * bmt[d];
            for (int k=0;k<D_;k++) acc += s_wc[k] * Wmt[k*D_ + d];
            s_ctx[d] = eluf(acc);
        }
        __syncthreads();
        for (int j=tid; j<G3D_; j+=256){
            float ai = mbih[j], ah = mbhh[j];
            const float* wi = mWih + (size_t)j*D_;
            const float* wh = mWhh + (size_t)j*D_;
            for (int k=0;k<D_;k++){ ai += s_ctx[k]*wi[k]; ah += s_mf[k]*wh[k]; }
            s_gi[j] = ai; s_gh[j] = ah;
        }
        __syncthreads();
        for (int d=tid; d<D_; d+=256){
            float rr = sigmf(s_gi[d] + s_gh[d]);
            float zz = sigmf(s_gi[D_+d] + s_gh[D_+d]);
            float nn = tanhf(s_gi[2*D_+d] + rr*s_gh[2*D_+d]);
            float nm = (1.f-zz)*nn + zz*s_mf[d];
            s_mf[d] = nm; s_act[d] = fmaxf(nm, 0.f);
        }
        __syncthreads();
    }
    const float dd = (float)(R_ - 2);
    float p = 0.f;
    for (int d=tid; d<D_; d+=256){
        float acc = bme[d];
        for (int k=0;k<D_;k++){
            float mf = s_mf[k];
            acc += mf * Wme[k*D_ + d];
            acc += (mf + dd) * Wme[(D_+k)*D_ + d];
        }
        p += acc * Wout[d];
    }
    float o = blockReduceSum(p, s_red);
    if (tid==0){
        o += bout[0];
        if (*amtag == FP32TAG) ((float*)out)[b] = o;
        else ((bf16*)out)[b] = __float2bfloat16(o);
    }
}

extern "C" void kernel_launch(void* const* d_in, const int* in_sizes, int n_in,
                              void* d_out, int out_size, void* d_ws, size_t ws_size,
                              hipStream_t stream) {
    const int* adl = (const int*)d_in[2];
    const int* bdl = (const int*)d_in[3];
    const unsigned* amtag = (const unsigned*)d_in[4];

    static const int srcidx[NSEG] = {0,1,4,5,6,7,8,9,10,11,12,15,16,17,18,19,20,21,22,23,24,25,26,27,28};
    static const int segsz[NSEG]  = {638976,327680,16384,7800,200,9800,200,1200,3,120000,600,
                                     1800,1800,400,1,40000,200,120000,120000,600,600,80000,200,200,1};
    CvtArgs ca;
    int ofs[NSEG+1]; ofs[0] = 0;
    for (int i=0;i<NSEG;i++){ ca.src[i] = d_in[srcidx[i]]; ca.ofs[i] = ofs[i]; ofs[i+1] = ofs[i] + segsz[i]; }
    ca.ofs[NSEG] = ofs[NSEG];
    const int total = ofs[NSEG];           // 1488645

    float* ws   = (float*)d_ws;
    float* conv = ws;
    float* Ti   = conv + ((total + 7) & ~7);
    float* Th   = Ti + R_*D_*G3D_;
    float* h    = Th + R_*D_*G3D_;
    float* cur  = h + BLD_;
    float* ctx  = cur + BLD_;          // also aliased as P (round-0 precompute, dead before ctxgemm)
    float* wnei = ctx + BLD_;
    float* s1   = wnei + BLD_;
    float* tb   = s1 + BL_;
    float* wsum = tb + BL_;
    float* P    = ctx;
    // total ws: ~61.6 MB

    const float* c_atom  = conv + ofs[0];
    const float* c_bond  = conv + ofs[1];
    const float* c_amask = conv + ofs[2];
    const float* c_Watom = conv + ofs[3];
    const float* c_batom = conv + ofs[4];
    const float* c_Wnei  = conv + ofs[5];
    const float* c_bnei  = conv + ofs[6];
    const float* c_Walign= conv + ofs[7];
    const float* c_balign= conv + ofs[8];
    const float* c_Watt  = conv + ofs[9];
    const float* c_batt  = conv + ofs[10];
    const float* c_bih   = conv + ofs[11];
    const float* c_bhh   = conv + ofs[12];
    const float* c_Wma   = conv + ofs[13];
    const float* c_bma   = conv + ofs[14];
    const float* c_Wmt   = conv + ofs[15];
    const float* c_bmt   = conv + ofs[16];
    const float* c_mWih  = conv + ofs[17];
    const float* c_mWhh  = conv + ofs[18];
    const float* c_mbih  = conv + ofs[19];
    const float* c_mbhh  = conv + ofs[20];
    const float* c_Wme   = conv + ofs[21];
    const float* c_bme   = conv + ofs[22];
    const float* c_Wout  = conv + ofs[23];
    const float* c_bout  = conv + ofs[24];

    k_convert<<<(total + 255)/256, 256, 0, stream>>>(ca, conv, amtag, total);
    k_transpose<<<(R_*D_*G3D_ + 255)/256, 256, 0, stream>>>(d_in[13], d_in[14], Ti, Th, amtag);
    k_atomfeat<<<BLD_/256, 256, 0, stream>>>(c_atom, c_Watom, c_batom, h, cur);
    k_precompP<<<BLD_/256, 256, 0, stream>>>(c_atom, c_Wnei, c_bnei, P);

    for (int r=0; r<R_; r++){
        k_dots<<<BL_/4, 256, 0, stream>>>(cur, c_Walign, r, s1, tb);
        k_attn<<<BL_/4, 256, 0, stream>>>(cur, s1, tb, adl, bdl, P, c_bond,
                                          c_Wnei, c_Walign, c_balign, r, wnei, wsum);
        k_ctxgemm<<<BL_/CTXA, 256, 0, stream>>>(wnei, wsum, c_Watt, c_batt, r, ctx);
        k_gruf<<<BL_/8, 256, 0, stream>>>(ctx, h, cur, Ti, Th, c_bih, c_bhh, r);
    }

    k_mol<<<B_, 256, 0, stream>>>(cur, c_amask, c_Wma, c_bma, c_Wmt, c_bmt,
                                  c_mWih, c_mWhh, c_mbih, c_mbhh, c_Wme, c_bme, c_Wout, c_bout,
                                  d_out, amtag);
}

// Round 6
// 680.396 us; speedup vs baseline: 1.8220x; 1.8220x over previous
//
#include <hip/hip_runtime.h>
#include <hip/hip_bf16.h>
#include <math.h>
#include <string.h>

#define B_ 128
#define L_ 128
#define N_ 6
#define FA_ 39
#define FB_ 10
#define D_ 200
#define MB_ 256
#define R_ 3
#define T_ 2
#define NEGV -9e8f
#define BL_ (B_*L_)        // 16384
#define BLD_ (BL_*D_)      // 3276800
#define G3D_ (3*D_)        // 600
#define FP32TAG 0x3F800000u
#define CTXA 16            // atoms per block in k_ctxgemm
#define KP 416             // padded K for gate GEMM (400 -> 416 = 13*32)
#define NP 832             // padded N for gate GEMM (800 -> 832 = 13*64)

typedef __hip_bfloat16 bf16;
typedef __attribute__((ext_vector_type(8))) short short8;
typedef __attribute__((ext_vector_type(4))) float f32x4;

__device__ __forceinline__ float b2f(const bf16 x){ return __bfloat162float(x); }
__device__ __forceinline__ unsigned short f2b(float v){ bf16 t = __float2bfloat16(v); return *reinterpret_cast<unsigned short*>(&t); }
__device__ __forceinline__ float bu2f(unsigned short u){ unsigned x = ((unsigned)u)<<16; float f; memcpy(&f,&x,4); return f; }
__device__ __forceinline__ float lreluf(float x){ return x>=0.f ? x : 0.01f*x; }
__device__ __forceinline__ float eluf(float x){ return x>0.f ? x : expm1f(x); }
__device__ __forceinline__ float sigmf(float x){ return 1.f/(1.f+expf(-x)); }

#define NSEG 25
struct CvtArgs { const void* src[NSEG]; int ofs[NSEG+1]; };

// canonicalize all float inputs (bf16 OR fp32 storage) to fp32 in ws
__global__ void k_convert(CvtArgs c, float* __restrict__ dst, const unsigned* __restrict__ amtag, int total){
    int i = blockIdx.x*blockDim.x + threadIdx.x;
    if (i >= total) return;
    bool f32 = (*amtag == FP32TAG);
    int s = 0;
    while (i >= c.ofs[s+1]) s++;
    int j = i - c.ofs[s];
    dst[i] = f32 ? ((const float*)c.src[s])[j] : b2f(((const bf16*)c.src[s])[j]);
}

// Build B2t[r][n][kk] (bf16, NP x KP per round) for the fused gate GEMM.
// Output col n: [0,200)=r-gate (xW+hW summed), [200,400)=z-gate (summed),
// [400,600)=gi_n (x half only), [600,800)=gh_n (h half only), [800,832)=zero.
__global__ void k_prepB(const void* __restrict__ Wih, const void* __restrict__ Whh,
                        unsigned short* __restrict__ B2t, const unsigned* __restrict__ amtag){
    int idx = blockIdx.x*blockDim.x + threadIdx.x;
    if (idx >= R_*NP*KP) return;
    bool f32 = (*amtag == FP32TAG);
    int kk = idx % KP;
    int rest = idx / KP;
    int n = rest % NP;
    int r = rest / NP;
    float v = 0.f;
    if (kk < 200){
        if (n < 600){
            size_t si = ((size_t)(r*G3D_ + n))*D_ + kk;
            v = f32 ? ((const float*)Wih)[si] : b2f(((const bf16*)Wih)[si]);
        }
    } else if (kk < 400){
        int j = -1;
        if (n < 400) j = n;                       // r,z gates: h half summed in
        else if (n >= 600 && n < 800) j = n - 200; // gh_n rows 400..600
        if (j >= 0){
            size_t si = ((size_t)(r*G3D_ + j))*D_ + (kk-200);
            v = f32 ? ((const float*)Whh)[si] : b2f(((const bf16*)Whh)[si]);
        }
    }
    B2t[idx] = f2b(v);
}

// atom_feature = lrelu(atom_list @ W_atom + b_atom); h = cur = atom_feature; XH h-half
__global__ void k_atomfeat(const float* __restrict__ atom_list, const float* __restrict__ W_atom,
                           const float* __restrict__ b_atom, float* __restrict__ h, float* __restrict__ cur,
                           unsigned short* __restrict__ XH){
    int idx = blockIdx.x*blockDim.x + threadIdx.x;
    if (idx >= BLD_) return;
    int d = idx % D_;
    int al = idx / D_;
    const float* arow = atom_list + (size_t)al*FA_;
    float acc = b_atom[d];
    for (int k=0;k<FA_;k++) acc += arow[k] * W_atom[k*D_ + d];
    float v = lreluf(acc);
    h[idx] = v; cur[idx] = v;
    XH[(size_t)al*KP + 200 + d] = f2b(v);
}

// zero the K-pad tail of XH (cols 400..416)
__global__ void k_xhpad(unsigned short* __restrict__ XH){
    int idx = blockIdx.x*blockDim.x + threadIdx.x;
    if (idx >= BL_*16) return;
    int al = idx >> 4, kk = 400 + (idx & 15);
    XH[(size_t)al*KP + kk] = 0;
}

// P = atom_list @ W_nei[0:FA] + b_nei  (atom half of round-0 neighbor features, pre-lrelu)
__global__ void k_precompP(const float* __restrict__ atom_list, const float* __restrict__ W_nei,
                           const float* __restrict__ b_nei, float* __restrict__ P){
    int idx = blockIdx.x*blockDim.x + threadIdx.x;
    if (idx >= BLD_) return;
    int d = idx % D_;
    int al = idx / D_;
    const float* arow = atom_list + (size_t)al*FA_;
    float acc = b_nei[d];
    for (int k=0;k<FA_;k++) acc += arow[k] * W_nei[k*D_ + d];
    P[idx] = acc;
}

// per-atom dots with W_align[r]: s1 = cur . Wa[0:D], tb = cur . Wa[D:2D]
__global__ void k_dots(const float* __restrict__ cur, const float* __restrict__ W_align, int r,
                       float* __restrict__ s1, float* __restrict__ tb){
    int wave = (blockIdx.x*blockDim.x + threadIdx.x) >> 6;
    int lane = threadIdx.x & 63;
    if (wave >= BL_) return;
    const float* Wa = W_align + r*2*D_;
    const float* row = cur + (size_t)wave*D_;
    float a1 = 0.f, a2 = 0.f;
    for (int k=lane; k<D_; k+=64){
        float c = row[k];
        a1 += c * Wa[k];
        a2 += c * Wa[D_+k];
    }
    for (int o=32;o>0;o>>=1){ a1 += __shfl_xor(a1,o); a2 += __shfl_xor(a2,o); }
    if (lane==0){ s1[wave]=a1; tb[wave]=a2; }
}

// attention: softmax + weighted neighbor sum. 4 atoms per 256-thread block, one wave per atom.
__global__ void __launch_bounds__(256) k_attn(
        const float* __restrict__ cur, const float* __restrict__ s1, const float* __restrict__ tb,
        const int* __restrict__ adl, const int* __restrict__ bdl,
        const float* __restrict__ P, const float* __restrict__ bond_list,
        const float* __restrict__ W_nei,
        const float* __restrict__ W_align, const float* __restrict__ b_align, int r,
        float* __restrict__ wnei, float* __restrict__ wsum){
    int wv = threadIdx.x >> 6;
    int lane = threadIdx.x & 63;
    int al = blockIdx.x*4 + wv;
    int bi = al >> 7;            // / L_
    __shared__ float s_nei[4][N_][D_];

    int idxn[N_]; bool pad[N_];
    for (int n=0;n<N_;n++){ idxn[n] = adl[al*N_ + n]; pad[n] = (idxn[n] == L_-1); }

    float s2[N_];
    if (r == 0){
        const float* Wb = W_nei + FA_*D_;
        for (int j = lane; j < N_*D_; j += 64){
            int n = j / D_, d = j - n*D_;
            int bd = bdl[al*N_ + n];
            const float* brow = bond_list + ((size_t)bi*MB_ + bd)*FB_;
            float acc = P[((size_t)bi*L_ + idxn[n])*D_ + d];
            #pragma unroll
            for (int k=0;k<FB_;k++) acc += brow[k] * Wb[k*D_ + d];
            s_nei[wv][n][d] = lreluf(acc);
        }
        const float* Wab = W_align + D_;
        for (int n=0;n<N_;n++){
            float acc = 0.f;
            for (int d=lane; d<D_; d+=64) acc += s_nei[wv][n][d] * Wab[d];
            for (int o=32;o>0;o>>=1) acc += __shfl_xor(acc,o);
            s2[n] = acc;
        }
    } else {
        float tmp = 0.f;
        if (lane < N_) tmp = tb[bi*L_ + idxn[lane]];
        for (int n=0;n<N_;n++) s2[n] = __shfl(tmp, n);
    }

    float s1v = s1[al];
    float bav = b_align[r];
    float a[N_]; float mx = -1e30f;
    for (int n=0;n<N_;n++){
        float v = lreluf(s1v + s2[n] + bav);
        if (pad[n]) v += NEGV;
        a[n] = v; mx = fmaxf(mx, v);
    }
    float w[N_]; float se = 0.f;
    for (int n=0;n<N_;n++){ float e = expf(a[n]-mx); w[n]=e; se += e; }
    float inv = 1.f/se; float wsv = 0.f;
    for (int n=0;n<N_;n++){ w[n] = pad[n] ? 0.f : w[n]*inv; wsv += w[n]; }

    if (r == 0){
        for (int d=lane; d<D_; d+=64){
            float acc = 0.f;
            #pragma unroll
            for (int n=0;n<N_;n++) acc += w[n] * s_nei[wv][n][d];
            wnei[(size_t)al*D_ + d] = acc;
        }
    } else {
        for (int d=lane; d<D_; d+=64){
            float acc = 0.f;
            #pragma unroll
            for (int n=0;n<N_;n++) acc += w[n] * cur[((size_t)bi*L_ + idxn[n])*D_ + d];
            wnei[(size_t)al*D_ + d] = acc;
        }
    }
    if (lane==0) wsum[al] = wsv;
}

// ctx = elu(wnei @ W_attend[r] + wsum * b_attend[r]) -> XH x-half (bf16)
__global__ void __launch_bounds__(256) k_ctxgemm(const float* __restrict__ wnei,
        const float* __restrict__ wsum,
        const float* __restrict__ W_attend, const float* __restrict__ b_attend, int r,
        unsigned short* __restrict__ XH){
    int tid = threadIdx.x;
    int al0 = blockIdx.x * CTXA;
    __shared__ float s_x[CTXA][D_];
    __shared__ float s_ws[CTXA];
    for (int i = tid; i < CTXA*D_; i += 256){
        int a = i / D_, d = i - a*D_;
        s_x[a][d] = wnei[(size_t)(al0+a)*D_ + d];
    }
    if (tid < CTXA) s_ws[tid] = wsum[al0 + tid];
    __syncthreads();
    int j = tid;
    if (j < D_){
        const float* W = W_attend + (size_t)r*D_*D_;
        float bv = b_attend[r*D_ + j];
        float acc[CTXA];
        #pragma unroll
        for (int a=0;a<CTXA;a++) acc[a] = 0.f;
        for (int k=0;k<D_;k+=4){
            float w0 = W[k*D_ + j], w1 = W[(k+1)*D_ + j];
            float w2 = W[(k+2)*D_ + j], w3 = W[(k+3)*D_ + j];
            #pragma unroll
            for (int a=0;a<CTXA;a++){
                float4 xv = *(const float4*)&s_x[a][k];
                acc[a] += xv.x*w0 + xv.y*w1 + xv.z*w2 + xv.w*w3;
            }
        }
        #pragma unroll
        for (int a=0;a<CTXA;a++)
            XH[(size_t)(al0+a)*KP + j] = f2b(eluf(acc[a] + s_ws[a]*bv));
    }
}

// MFMA bf16 gate GEMM: C[16384,NP] = XH[16384,KP] @ B2t[r]^T  (B2t stored n-major [NP][KP])
// 64x64 tile per 256-thread block; 4 waves, each: 16 rows x (4 x 16 cols), K-steps of 32.
__global__ void __launch_bounds__(256) k_gemm(const unsigned short* __restrict__ XH,
        const unsigned short* __restrict__ B2t, unsigned short* __restrict__ C, int r){
    __shared__ unsigned short As[64][40];
    __shared__ unsigned short Bs[64][40];
    int tid = threadIdx.x;
    int bid = blockIdx.x;
    int m0 = (bid & 255) * 64;
    int n0 = (bid >> 8) * 64;
    const unsigned short* Bt = B2t + (size_t)r*NP*KP;
    int lane = tid & 63, wm = tid >> 6;
    int quad = lane >> 4, lm = lane & 15;
    f32x4 acc0 = {0.f,0.f,0.f,0.f}, acc1 = acc0, acc2 = acc0, acc3 = acc0;
    int srow = tid >> 2, schunk = (tid & 3) * 8;
    for (int ks = 0; ks < 13; ks++){
        __syncthreads();
        *(uint4*)&As[srow][schunk] = *(const uint4*)&XH[(size_t)(m0 + srow)*KP + ks*32 + schunk];
        *(uint4*)&Bs[srow][schunk] = *(const uint4*)&Bt[(size_t)(n0 + srow)*KP + ks*32 + schunk];
        __syncthreads();
        short8 av = *(const short8*)&As[16*wm + lm][quad*8];
        short8 b0 = *(const short8*)&Bs[lm][quad*8];
        short8 b1 = *(const short8*)&Bs[16 + lm][quad*8];
        short8 b2 = *(const short8*)&Bs[32 + lm][quad*8];
        short8 b3 = *(const short8*)&Bs[48 + lm][quad*8];
        acc0 = __builtin_amdgcn_mfma_f32_16x16x32_bf16(av, b0, acc0, 0, 0, 0);
        acc1 = __builtin_amdgcn_mfma_f32_16x16x32_bf16(av, b1, acc1, 0, 0, 0);
        acc2 = __builtin_amdgcn_mfma_f32_16x16x32_bf16(av, b2, acc2, 0, 0, 0);
        acc3 = __builtin_amdgcn_mfma_f32_16x16x32_bf16(av, b3, acc3, 0, 0, 0);
    }
    // C/D layout: col = lane&15, row = quad*4 + reg
    #pragma unroll
    for (int i=0;i<4;i++){
        size_t rowbase = (size_t)(m0 + 16*wm + quad*4 + i)*NP + n0 + lm;
        C[rowbase      ] = f2b(acc0[i]);
        C[rowbase + 16 ] = f2b(acc1[i]);
        C[rowbase + 32 ] = f2b(acc2[i]);
        C[rowbase + 48 ] = f2b(acc3[i]);
    }
}

// GRU combine from gate GEMM output C: cols [0,200)=rsum, [200,400)=zsum, [400,600)=gi_n, [600,800)=gh_n
__global__ void k_gru2(const unsigned short* __restrict__ C, float* __restrict__ h,
        float* __restrict__ cur, unsigned short* __restrict__ XH,
        const float* __restrict__ bih, const float* __restrict__ bhh, int r){
    int idx = blockIdx.x*blockDim.x + threadIdx.x;
    if (idx >= BLD_) return;
    int j = idx % D_;
    int al = idx / D_;
    size_t base = (size_t)al*NP;
    float rsum = bu2f(C[base + j]);
    float zsum = bu2f(C[base + 200 + j]);
    float gin  = bu2f(C[base + 400 + j]);
    float ghn  = bu2f(C[base + 600 + j]);
    const float* bi = bih + r*G3D_;
    const float* bh = bhh + r*G3D_;
    float rr = sigmf(rsum + bi[j] + bh[j]);
    float zz = sigmf(zsum + bi[D_+j] + bh[D_+j]);
    float nn = tanhf(gin + bi[2*D_+j] + rr*(ghn + bh[2*D_+j]));
    float hv = h[idx];
    float hn = (1.f-zz)*nn + zz*hv;
    h[idx] = hn;
    cur[idx] = fmaxf(hn, 0.f);
    XH[(size_t)al*KP + 200 + j] = f2b(hn);   // h-half for next round's gate GEMM
}

__device__ __forceinline__ float blockReduceSum(float v, float* s_red){
    for (int o=32;o>0;o>>=1) v += __shfl_xor(v,o);
    int lane = threadIdx.x & 63, wid = threadIdx.x >> 6;
    __syncthreads();
    if (lane==0) s_red[wid] = v;
    __syncthreads();
    float r = s_red[0];
    int nw = blockDim.x >> 6;
    for (int i=1;i<nw;i++) r += s_red[i];
    return r;
}

// molecule phase: pooling, T mol-attention+GRU steps, output head. One block per molecule.
__global__ void __launch_bounds__(256) k_mol(const float* __restrict__ cur, const float* __restrict__ atom_mask,
    const float* __restrict__ Wma, const float* __restrict__ bma,
    const float* __restrict__ Wmt, const float* __restrict__ bmt,
    const float* __restrict__ mWih, const float* __restrict__ mWhh,
    const float* __restrict__ mbih, const float* __restrict__ mbhh,
    const float* __restrict__ Wme, const float* __restrict__ bme,
    const float* __restrict__ Wout, const float* __restrict__ bout,
    void* __restrict__ out, const unsigned* __restrict__ amtag){
    int b = blockIdx.x, tid = threadIdx.x;
    __shared__ float s_am[L_], s_neg[L_], s_mf[D_], s_act[D_], s_sc[L_], s_w[L_];
    __shared__ float s_wc[D_], s_ctx[D_], s_gi[G3D_], s_gh[G3D_], s_red[8];
    const float* curb = cur + (size_t)b*L_*D_;
    if (tid < L_){
        float am = atom_mask[b*L_ + tid];
        s_am[tid] = am;
        s_neg[tid] = (am == 0.f) ? NEGV : 0.f;
    }
    __syncthreads();
    for (int d=tid; d<D_; d+=256){
        float acc = 0.f;
        for (int l=0;l<L_;l++) acc += curb[l*D_ + d] * s_am[l];
        s_mf[d] = acc; s_act[d] = fmaxf(acc, 0.f);
    }
    __syncthreads();
    for (int t=0;t<T_;t++){
        float p = 0.f;
        for (int d=tid; d<D_; d+=256) p += s_act[d] * Wma[d];
        float s1 = blockReduceSum(p, s_red);
        if (tid < L_){
            const float* row = curb + tid*D_;
            float sc = 0.f;
            for (int d=0; d<D_; d++) sc += row[d] * Wma[D_+d];
            sc = lreluf(s1 + sc + bma[0]);
            s_sc[tid] = sc + s_neg[tid];
        }
        __syncthreads();
        if (tid==0){ float mx=-1e30f; for (int l=0;l<L_;l++) mx=fmaxf(mx,s_sc[l]); s_red[4]=mx; }
        __syncthreads();
        if (tid < L_) s_w[tid] = expf(s_sc[tid] - s_red[4]);
        __syncthreads();
        if (tid==0){ float sm=0.f; for (int l=0;l<L_;l++) sm+=s_w[l]; s_red[5]=sm; }
        __syncthreads();
        if (tid < L_) s_w[tid] = s_w[tid]/s_red[5]*s_am[tid];
        __syncthreads();
        if (tid==0){ float sm=0.f; for (int l=0;l<L_;l++) sm+=s_w[l]; s_red[6]=sm; }
        __syncthreads();
        for (int d=tid; d<D_; d+=256){
            float acc = 0.f;
            for (int l=0;l<L_;l++) acc += s_w[l]*curb[l*D_ + d];
            s_wc[d] = acc;
        }
        __syncthreads();
        float wsm = s_red[6];
        for (int d=tid; d<D_; d+=256){
            float acc = wsm * bmt[d];
            for (int k=0;k<D_;k++) acc += s_wc[k] * Wmt[k*D_ + d];
            s_ctx[d] = eluf(acc);
        }
        __syncthreads();
        for (int j=tid; j<G3D_; j+=256){
            float ai = mbih[j], ah = mbhh[j];
            const float* wi = mWih + (size_t)j*D_;
            const float* wh = mWhh + (size_t)j*D_;
            for (int k=0;k<D_;k++){ ai += s_ctx[k]*wi[k]; ah += s_mf[k]*wh[k]; }
            s_gi[j] = ai; s_gh[j] = ah;
        }
        __syncthreads();
        for (int d=tid; d<D_; d+=256){
            float rr = sigmf(s_gi[d] + s_gh[d]);
            float zz = sigmf(s_gi[D_+d] + s_gh[D_+d]);
            float nn = tanhf(s_gi[2*D_+d] + rr*s_gh[2*D_+d]);
            float nm = (1.f-zz)*nn + zz*s_mf[d];
            s_mf[d] = nm; s_act[d] = fmaxf(nm, 0.f);
        }
        __syncthreads();
    }
    const float dd = (float)(R_ - 2);
    float p = 0.f;
    for (int d=tid; d<D_; d+=256){
        float acc = bme[d];
        for (int k=0;k<D_;k++){
            float mf = s_mf[k];
            acc += mf * Wme[k*D_ + d];
            acc += (mf + dd) * Wme[(D_+k)*D_ + d];
        }
        p += acc * Wout[d];
    }
    float o = blockReduceSum(p, s_red);
    if (tid==0){
        o += bout[0];
        if (*amtag == FP32TAG) ((float*)out)[b] = o;
        else ((bf16*)out)[b] = __float2bfloat16(o);
    }
}

extern "C" void kernel_launch(void* const* d_in, const int* in_sizes, int n_in,
                              void* d_out, int out_size, void* d_ws, size_t ws_size,
                              hipStream_t stream) {
    const int* adl = (const int*)d_in[2];
    const int* bdl = (const int*)d_in[3];
    const unsigned* amtag = (const unsigned*)d_in[4];

    static const int srcidx[NSEG] = {0,1,4,5,6,7,8,9,10,11,12,15,16,17,18,19,20,21,22,23,24,25,26,27,28};
    static const int segsz[NSEG]  = {638976,327680,16384,7800,200,9800,200,1200,3,120000,600,
                                     1800,1800,400,1,40000,200,120000,120000,600,600,80000,200,200,1};
    CvtArgs ca;
    int ofs[NSEG+1]; ofs[0] = 0;
    for (int i=0;i<NSEG;i++){ ca.src[i] = d_in[srcidx[i]]; ca.ofs[i] = ofs[i]; ofs[i+1] = ofs[i] + segsz[i]; }
    ca.ofs[NSEG] = ofs[NSEG];
    const int total = ofs[NSEG];           // 1488645

    // ws layout (floats; every offset multiple of 4 -> 16B aligned). ~75.3 MB total.
    float* ws   = (float*)d_ws;
    float* conv = ws;                                   // 1488648 (padded)
    float* h    = conv + 1488648;                       // BLD_
    float* cur  = h + BLD_;                             // BLD_
    unsigned short* XH  = (unsigned short*)(cur + BLD_);        // BL_*KP shorts = 3407872 f-equiv
    unsigned short* B2t = XH + (size_t)BL_*KP;                  // R_*NP*KP shorts = 519168 f-equiv
    float* creg = (float*)(B2t + (size_t)R_*NP*KP);             // C region: BL_*NP shorts = 6815744 f-equiv
    unsigned short* C = (unsigned short*)creg;
    float* wnei = creg;                                 // overlays C (dead before k_gemm writes C)
    float* P    = creg + BLD_;                          // overlays C tail (round-0 only)
    float* s1   = creg + (size_t)BL_*NP/2;              // after C region
    float* tb   = s1 + BL_;
    float* wsum = tb + BL_;

    const float* c_atom  = conv + ofs[0];
    const float* c_bond  = conv + ofs[1];
    const float* c_amask = conv + ofs[2];
    const float* c_Watom = conv + ofs[3];
    const float* c_batom = conv + ofs[4];
    const float* c_Wnei  = conv + ofs[5];
    const float* c_bnei  = conv + ofs[6];
    const float* c_Walign= conv + ofs[7];
    const float* c_balign= conv + ofs[8];
    const float* c_Watt  = conv + ofs[9];
    const float* c_batt  = conv + ofs[10];
    const float* c_bih   = conv + ofs[11];
    const float* c_bhh   = conv + ofs[12];
    const float* c_Wma   = conv + ofs[13];
    const float* c_bma   = conv + ofs[14];
    const float* c_Wmt   = conv + ofs[15];
    const float* c_bmt   = conv + ofs[16];
    const float* c_mWih  = conv + ofs[17];
    const float* c_mWhh  = conv + ofs[18];
    const float* c_mbih  = conv + ofs[19];
    const float* c_mbhh  = conv + ofs[20];
    const float* c_Wme   = conv + ofs[21];
    const float* c_bme   = conv + ofs[22];
    const float* c_Wout  = conv + ofs[23];
    const float* c_bout  = conv + ofs[24];

    k_convert<<<(total + 255)/256, 256, 0, stream>>>(ca, conv, amtag, total);
    k_prepB<<<(R_*NP*KP + 255)/256, 256, 0, stream>>>(d_in[13], d_in[14], B2t, amtag);
    k_atomfeat<<<BLD_/256, 256, 0, stream>>>(c_atom, c_Watom, c_batom, h, cur, XH);
    k_xhpad<<<(BL_*16)/256, 256, 0, stream>>>(XH);
    k_precompP<<<BLD_/256, 256, 0, stream>>>(c_atom, c_Wnei, c_bnei, P);

    for (int r=0; r<R_; r++){
        k_dots<<<BL_/4, 256, 0, stream>>>(cur, c_Walign, r, s1, tb);
        k_attn<<<BL_/4, 256, 0, stream>>>(cur, s1, tb, adl, bdl, P, c_bond,
                                          c_Wnei, c_Walign, c_balign, r, wnei, wsum);
        k_ctxgemm<<<BL_/CTXA, 256, 0, stream>>>(wnei, wsum, c_Watt, c_batt, r, XH);
        k_gemm<<<(BL_/64)*(NP/64), 256, 0, stream>>>(XH, B2t, C, r);
        k_gru2<<<BLD_/256, 256, 0, stream>>>(C, h, cur, XH, c_bih, c_bhh, r);
    }

    k_mol<<<B_, 256, 0, stream>>>(cur, c_amask, c_Wma, c_bma, c_Wmt, c_bmt,
                                  c_mWih, c_mWhh, c_mbih, c_mbhh, c_Wme, c_bme, c_Wout, c_bout,
                                  d_out, amtag);
}

// Round 7
// 660.685 us; speedup vs baseline: 1.8764x; 1.0298x over previous
//
#include <hip/hip_runtime.h>
#include <hip/hip_bf16.h>
#include <math.h>
#include <string.h>

#define B_ 128
#define L_ 128
#define N_ 6
#define FA_ 39
#define FB_ 10
#define D_ 200
#define MB_ 256
#define R_ 3
#define T_ 2
#define NEGV -9e8f
#define BL_ (B_*L_)        // 16384
#define BLD_ (BL_*D_)      // 3276800
#define G3D_ (3*D_)        // 600
#define FP32TAG 0x3F800000u
#define CTXA 16            // atoms per block in k_ctxgemm
#define KP 416             // padded K for gate GEMM (400 -> 416 = 13*32)
#define NP 832             // padded N for gate GEMM (800 -> 832 = 13*64)

typedef __hip_bfloat16 bf16;
typedef __attribute__((ext_vector_type(8))) short short8;
typedef __attribute__((ext_vector_type(4))) float f32x4;

__device__ __forceinline__ float b2f(const bf16 x){ return __bfloat162float(x); }
__device__ __forceinline__ unsigned short f2b(float v){ bf16 t = __float2bfloat16(v); return *reinterpret_cast<unsigned short*>(&t); }
__device__ __forceinline__ float bu2f(unsigned short u){ unsigned x = ((unsigned)u)<<16; float f; memcpy(&f,&x,4); return f; }
__device__ __forceinline__ float lreluf(float x){ return x>=0.f ? x : 0.01f*x; }
__device__ __forceinline__ float eluf(float x){ return x>0.f ? x : expm1f(x); }
__device__ __forceinline__ float sigmf(float x){ return 1.f/(1.f+expf(-x)); }

#define NSEG 25
struct CvtArgs { const void* src[NSEG]; int ofs[NSEG+1]; };

// canonicalize all float inputs (bf16 OR fp32 storage) to fp32 in ws
__global__ void k_convert(CvtArgs c, float* __restrict__ dst, const unsigned* __restrict__ amtag, int total){
    int i = blockIdx.x*blockDim.x + threadIdx.x;
    if (i >= total) return;
    bool f32 = (*amtag == FP32TAG);
    int s = 0;
    while (i >= c.ofs[s+1]) s++;
    int j = i - c.ofs[s];
    dst[i] = f32 ? ((const float*)c.src[s])[j] : b2f(((const bf16*)c.src[s])[j]);
}

// Build B2t[r][n][kk] (bf16, NP x KP per round) for the fused gate GEMM.
__global__ void k_prepB(const void* __restrict__ Wih, const void* __restrict__ Whh,
                        unsigned short* __restrict__ B2t, const unsigned* __restrict__ amtag){
    int idx = blockIdx.x*blockDim.x + threadIdx.x;
    if (idx >= R_*NP*KP) return;
    bool f32 = (*amtag == FP32TAG);
    int kk = idx % KP;
    int rest = idx / KP;
    int n = rest % NP;
    int r = rest / NP;
    float v = 0.f;
    if (kk < 200){
        if (n < 600){
            size_t si = ((size_t)(r*G3D_ + n))*D_ + kk;
            v = f32 ? ((const float*)Wih)[si] : b2f(((const bf16*)Wih)[si]);
        }
    } else if (kk < 400){
        int j = -1;
        if (n < 400) j = n;
        else if (n >= 600 && n < 800) j = n - 200;
        if (j >= 0){
            size_t si = ((size_t)(r*G3D_ + j))*D_ + (kk-200);
            v = f32 ? ((const float*)Whh)[si] : b2f(((const bf16*)Whh)[si]);
        }
    }
    B2t[idx] = f2b(v);
}

// transpose mol GRU weights [600][200] -> [200][600] for coalesced k_mol gate loads
__global__ void k_prepM(const float* __restrict__ mWih, const float* __restrict__ mWhh,
                        float* __restrict__ mTi, float* __restrict__ mTh){
    int idx = blockIdx.x*blockDim.x + threadIdx.x;
    if (idx >= D_*G3D_) return;
    int j = idx % G3D_, k = idx / G3D_;
    mTi[idx] = mWih[(size_t)j*D_ + k];
    mTh[idx] = mWhh[(size_t)j*D_ + k];
}

// fused init: atom_feature + P + XH h-half + XH pad
__global__ void k_init(const float* __restrict__ atom_list,
                       const float* __restrict__ W_atom, const float* __restrict__ b_atom,
                       const float* __restrict__ W_nei, const float* __restrict__ b_nei,
                       float* __restrict__ h, float* __restrict__ cur,
                       unsigned short* __restrict__ XH, float* __restrict__ P){
    int idx = blockIdx.x*blockDim.x + threadIdx.x;
    if (idx < BL_*16){
        int al = idx >> 4, kk = 400 + (idx & 15);
        XH[(size_t)al*KP + kk] = 0;
    }
    if (idx >= BLD_) return;
    int d = idx % D_;
    int al = idx / D_;
    const float* arow = atom_list + (size_t)al*FA_;
    float acc1 = b_atom[d], acc2 = b_nei[d];
    for (int k=0;k<FA_;k++){
        float a = arow[k];
        acc1 += a * W_atom[k*D_ + d];
        acc2 += a * W_nei[k*D_ + d];
    }
    float v = lreluf(acc1);
    h[idx] = v; cur[idx] = v;
    XH[(size_t)al*KP + 200 + d] = f2b(v);
    P[idx] = acc2;
}

// per-atom dots with W_align[r]: s1 = cur . Wa[0:D], tb = cur . Wa[D:2D]
__global__ void k_dots(const float* __restrict__ cur, const float* __restrict__ W_align, int r,
                       float* __restrict__ s1, float* __restrict__ tb){
    int wave = (blockIdx.x*blockDim.x + threadIdx.x) >> 6;
    int lane = threadIdx.x & 63;
    if (wave >= BL_) return;
    const float* Wa = W_align + r*2*D_;
    const float* row = cur + (size_t)wave*D_;
    float a1 = 0.f, a2 = 0.f;
    for (int k=lane; k<D_; k+=64){
        float c = row[k];
        a1 += c * Wa[k];
        a2 += c * Wa[D_+k];
    }
    for (int o=32;o>0;o>>=1){ a1 += __shfl_xor(a1,o); a2 += __shfl_xor(a2,o); }
    if (lane==0){ s1[wave]=a1; tb[wave]=a2; }
}

// curdot[al] = cur[al] . Wma[D:2D]  (t-invariant mol attention score half)
__global__ void k_moldot(const float* __restrict__ cur, const float* __restrict__ Wma,
                         float* __restrict__ curdot){
    int wave = (blockIdx.x*blockDim.x + threadIdx.x) >> 6;
    int lane = threadIdx.x & 63;
    if (wave >= BL_) return;
    const float* row = cur + (size_t)wave*D_;
    float a = 0.f;
    for (int k=lane; k<D_; k+=64) a += row[k] * Wma[D_+k];
    for (int o=32;o>0;o>>=1) a += __shfl_xor(a,o);
    if (lane==0) curdot[wave] = a;
}

// attention: softmax + weighted neighbor sum. 4 atoms per 256-thread block, one wave per atom.
__global__ void __launch_bounds__(256) k_attn(
        const float* __restrict__ cur, const float* __restrict__ s1, const float* __restrict__ tb,
        const int* __restrict__ adl, const int* __restrict__ bdl,
        const float* __restrict__ P, const float* __restrict__ bond_list,
        const float* __restrict__ W_nei,
        const float* __restrict__ W_align, const float* __restrict__ b_align, int r,
        float* __restrict__ wnei, float* __restrict__ wsum){
    int wv = threadIdx.x >> 6;
    int lane = threadIdx.x & 63;
    int al = blockIdx.x*4 + wv;
    int bi = al >> 7;            // / L_
    __shared__ float s_nei[4][N_][D_];

    int idxn[N_]; bool pad[N_];
    for (int n=0;n<N_;n++){ idxn[n] = adl[al*N_ + n]; pad[n] = (idxn[n] == L_-1); }

    float s2[N_];
    if (r == 0){
        const float* Wb = W_nei + FA_*D_;
        for (int j = lane; j < N_*D_; j += 64){
            int n = j / D_, d = j - n*D_;
            int bd = bdl[al*N_ + n];
            const float* brow = bond_list + ((size_t)bi*MB_ + bd)*FB_;
            float acc = P[((size_t)bi*L_ + idxn[n])*D_ + d];
            #pragma unroll
            for (int k=0;k<FB_;k++) acc += brow[k] * Wb[k*D_ + d];
            s_nei[wv][n][d] = lreluf(acc);
        }
        const float* Wab = W_align + D_;
        for (int n=0;n<N_;n++){
            float acc = 0.f;
            for (int d=lane; d<D_; d+=64) acc += s_nei[wv][n][d] * Wab[d];
            for (int o=32;o>0;o>>=1) acc += __shfl_xor(acc,o);
            s2[n] = acc;
        }
    } else {
        float tmp = 0.f;
        if (lane < N_) tmp = tb[bi*L_ + idxn[lane]];
        for (int n=0;n<N_;n++) s2[n] = __shfl(tmp, n);
    }

    float s1v = s1[al];
    float bav = b_align[r];
    float a[N_]; float mx = -1e30f;
    for (int n=0;n<N_;n++){
        float v = lreluf(s1v + s2[n] + bav);
        if (pad[n]) v += NEGV;
        a[n] = v; mx = fmaxf(mx, v);
    }
    float w[N_]; float se = 0.f;
    for (int n=0;n<N_;n++){ float e = expf(a[n]-mx); w[n]=e; se += e; }
    float inv = 1.f/se; float wsv = 0.f;
    for (int n=0;n<N_;n++){ w[n] = pad[n] ? 0.f : w[n]*inv; wsv += w[n]; }

    if (r == 0){
        for (int d=lane; d<D_; d+=64){
            float acc = 0.f;
            #pragma unroll
            for (int n=0;n<N_;n++) acc += w[n] * s_nei[wv][n][d];
            wnei[(size_t)al*D_ + d] = acc;
        }
    } else {
        for (int d=lane; d<D_; d+=64){
            float acc = 0.f;
            #pragma unroll
            for (int n=0;n<N_;n++) acc += w[n] * cur[((size_t)bi*L_ + idxn[n])*D_ + d];
            wnei[(size_t)al*D_ + d] = acc;
        }
    }
    if (lane==0) wsum[al] = wsv;
}

// ctx = elu(wnei @ W_attend[r] + wsum * b_attend[r]) -> XH x-half (bf16)
__global__ void __launch_bounds__(256) k_ctxgemm(const float* __restrict__ wnei,
        const float* __restrict__ wsum,
        const float* __restrict__ W_attend, const float* __restrict__ b_attend, int r,
        unsigned short* __restrict__ XH){
    int tid = threadIdx.x;
    int al0 = blockIdx.x * CTXA;
    __shared__ float s_x[CTXA][D_];
    __shared__ float s_ws[CTXA];
    for (int i = tid; i < CTXA*D_; i += 256){
        int a = i / D_, d = i - a*D_;
        s_x[a][d] = wnei[(size_t)(al0+a)*D_ + d];
    }
    if (tid < CTXA) s_ws[tid] = wsum[al0 + tid];
    __syncthreads();
    int j = tid;
    if (j < D_){
        const float* W = W_attend + (size_t)r*D_*D_;
        float bv = b_attend[r*D_ + j];
        float acc[CTXA];
        #pragma unroll
        for (int a=0;a<CTXA;a++) acc[a] = 0.f;
        for (int k=0;k<D_;k+=4){
            float w0 = W[k*D_ + j], w1 = W[(k+1)*D_ + j];
            float w2 = W[(k+2)*D_ + j], w3 = W[(k+3)*D_ + j];
            #pragma unroll
            for (int a=0;a<CTXA;a++){
                float4 xv = *(const float4*)&s_x[a][k];
                acc[a] += xv.x*w0 + xv.y*w1 + xv.z*w2 + xv.w*w3;
            }
        }
        #pragma unroll
        for (int a=0;a<CTXA;a++)
            XH[(size_t)(al0+a)*KP + j] = f2b(eluf(acc[a] + s_ws[a]*bv));
    }
}

// MFMA bf16 gate GEMM: C[16384,NP] = XH[16384,KP] @ B2t[r]^T
__global__ void __launch_bounds__(256) k_gemm(const unsigned short* __restrict__ XH,
        const unsigned short* __restrict__ B2t, unsigned short* __restrict__ C, int r){
    __shared__ unsigned short As[64][40];
    __shared__ unsigned short Bs[64][40];
    int tid = threadIdx.x;
    int bid = blockIdx.x;
    int m0 = (bid & 255) * 64;
    int n0 = (bid >> 8) * 64;
    const unsigned short* Bt = B2t + (size_t)r*NP*KP;
    int lane = tid & 63, wm = tid >> 6;
    int quad = lane >> 4, lm = lane & 15;
    f32x4 acc0 = {0.f,0.f,0.f,0.f}, acc1 = acc0, acc2 = acc0, acc3 = acc0;
    int srow = tid >> 2, schunk = (tid & 3) * 8;
    for (int ks = 0; ks < 13; ks++){
        __syncthreads();
        *(uint4*)&As[srow][schunk] = *(const uint4*)&XH[(size_t)(m0 + srow)*KP + ks*32 + schunk];
        *(uint4*)&Bs[srow][schunk] = *(const uint4*)&Bt[(size_t)(n0 + srow)*KP + ks*32 + schunk];
        __syncthreads();
        short8 av = *(const short8*)&As[16*wm + lm][quad*8];
        short8 b0 = *(const short8*)&Bs[lm][quad*8];
        short8 b1 = *(const short8*)&Bs[16 + lm][quad*8];
        short8 b2 = *(const short8*)&Bs[32 + lm][quad*8];
        short8 b3 = *(const short8*)&Bs[48 + lm][quad*8];
        acc0 = __builtin_amdgcn_mfma_f32_16x16x32_bf16(av, b0, acc0, 0, 0, 0);
        acc1 = __builtin_amdgcn_mfma_f32_16x16x32_bf16(av, b1, acc1, 0, 0, 0);
        acc2 = __builtin_amdgcn_mfma_f32_16x16x32_bf16(av, b2, acc2, 0, 0, 0);
        acc3 = __builtin_amdgcn_mfma_f32_16x16x32_bf16(av, b3, acc3, 0, 0, 0);
    }
    #pragma unroll
    for (int i=0;i<4;i++){
        size_t rowbase = (size_t)(m0 + 16*wm + quad*4 + i)*NP + n0 + lm;
        C[rowbase      ] = f2b(acc0[i]);
        C[rowbase + 16 ] = f2b(acc1[i]);
        C[rowbase + 32 ] = f2b(acc2[i]);
        C[rowbase + 48 ] = f2b(acc3[i]);
    }
}

// GRU combine from gate GEMM output C
__global__ void k_gru2(const unsigned short* __restrict__ C, float* __restrict__ h,
        float* __restrict__ cur, unsigned short* __restrict__ XH,
        const float* __restrict__ bih, const float* __restrict__ bhh, int r){
    int idx = blockIdx.x*blockDim.x + threadIdx.x;
    if (idx >= BLD_) return;
    int j = idx % D_;
    int al = idx / D_;
    size_t base = (size_t)al*NP;
    float rsum = bu2f(C[base + j]);
    float zsum = bu2f(C[base + 200 + j]);
    float gin  = bu2f(C[base + 400 + j]);
    float ghn  = bu2f(C[base + 600 + j]);
    const float* bi = bih + r*G3D_;
    const float* bh = bhh + r*G3D_;
    float rr = sigmf(rsum + bi[j] + bh[j]);
    float zz = sigmf(zsum + bi[D_+j] + bh[D_+j]);
    float nn = tanhf(gin + bi[2*D_+j] + rr*(ghn + bh[2*D_+j]));
    float hv = h[idx];
    float hn = (1.f-zz)*nn + zz*hv;
    h[idx] = hn;
    cur[idx] = fmaxf(hn, 0.f);
    XH[(size_t)al*KP + 200 + j] = f2b(hn);
}

__device__ __forceinline__ float blockReduceSum(float v, float* s_red){
    for (int o=32;o>0;o>>=1) v += __shfl_xor(v,o);
    int lane = threadIdx.x & 63, wid = threadIdx.x >> 6;
    __syncthreads();
    if (lane==0) s_red[wid] = v;
    __syncthreads();
    float r = s_red[0];
    int nw = blockDim.x >> 6;
    for (int i=1;i<nw;i++) r += s_red[i];
    return r;
}

__device__ __forceinline__ float blockReduceMax(float v, float* s_red){
    for (int o=32;o>0;o>>=1) v = fmaxf(v, __shfl_xor(v,o));
    int lane = threadIdx.x & 63, wid = threadIdx.x >> 6;
    __syncthreads();
    if (lane==0) s_red[wid] = v;
    __syncthreads();
    float r = s_red[0];
    int nw = blockDim.x >> 6;
    for (int i=1;i<nw;i++) r = fmaxf(r, s_red[i]);
    return r;
}

// molecule phase: pooling, T mol-attention+GRU steps, output head. One block per molecule.
// All reductions parallel; gate weights pre-transposed (mTi/mTh [k][j]); score dot precomputed.
__global__ void __launch_bounds__(256) k_mol(const float* __restrict__ cur,
    const float* __restrict__ curdot, const float* __restrict__ atom_mask,
    const float* __restrict__ Wma, const float* __restrict__ bma,
    const float* __restrict__ Wmt, const float* __restrict__ bmt,
    const float* __restrict__ mTi, const float* __restrict__ mTh,
    const float* __restrict__ mbih, const float* __restrict__ mbhh,
    const float* __restrict__ Wme, const float* __restrict__ bme,
    const float* __restrict__ Wout, const float* __restrict__ bout,
    void* __restrict__ out, const unsigned* __restrict__ amtag){
    int b = blockIdx.x, tid = threadIdx.x;
    __shared__ float s_am[L_], s_neg[L_], s_cd[L_], s_mf[D_], s_act[D_], s_w[L_];
    __shared__ float s_wc[D_], s_ctx[D_], s_gi[G3D_], s_gh[G3D_], s_red[8];
    const float* curb = cur + (size_t)b*L_*D_;
    if (tid < L_){
        float am = atom_mask[b*L_ + tid];
        s_am[tid] = am;
        s_neg[tid] = (am == 0.f) ? NEGV : 0.f;
        s_cd[tid] = curdot[b*L_ + tid];
    }
    __syncthreads();
    for (int d=tid; d<D_; d+=256){
        float acc = 0.f;
        for (int l=0;l<L_;l++) acc += curb[l*D_ + d] * s_am[l];
        s_mf[d] = acc; s_act[d] = fmaxf(acc, 0.f);
    }
    __syncthreads();
    float bma0 = bma[0];
    for (int t=0;t<T_;t++){
        float p = 0.f;
        for (int d=tid; d<D_; d+=256) p += s_act[d] * Wma[d];
        float s1 = blockReduceSum(p, s_red);
        float sc = (tid < L_) ? (lreluf(s1 + s_cd[tid] + bma0) + s_neg[tid]) : -1e30f;
        float mx = blockReduceMax(sc, s_red);
        float e = (tid < L_) ? expf(sc - mx) : 0.f;
        float se = blockReduceSum(e, s_red);
        float wv = (tid < L_) ? e/se*s_am[tid] : 0.f;
        if (tid < L_) s_w[tid] = wv;
        float wsm = blockReduceSum(wv, s_red);
        __syncthreads();
        for (int d=tid; d<D_; d+=256){
            float acc = 0.f;
            for (int l=0;l<L_;l++) acc += s_w[l]*curb[l*D_ + d];
            s_wc[d] = acc;
        }
        __syncthreads();
        if (tid < D_){
            float acc = wsm * bmt[tid];
            for (int k=0;k<D_;k++) acc += s_wc[k] * Wmt[k*D_ + tid];
            s_ctx[tid] = eluf(acc);
        }
        __syncthreads();
        for (int j=tid; j<G3D_; j+=256){
            float ai = 0.f, ah = 0.f;
            for (int k=0;k<D_;k++){
                ai += s_ctx[k] * mTi[(size_t)k*G3D_ + j];
                ah += s_mf[k]  * mTh[(size_t)k*G3D_ + j];
            }
            s_gi[j] = ai; s_gh[j] = ah;
        }
        __syncthreads();
        if (tid < D_){
            int d = tid;
            float rr = sigmf(s_gi[d] + mbih[d] + s_gh[d] + mbhh[d]);
            float zz = sigmf(s_gi[D_+d] + mbih[D_+d] + s_gh[D_+d] + mbhh[D_+d]);
            float nn = tanhf(s_gi[2*D_+d] + mbih[2*D_+d] + rr*(s_gh[2*D_+d] + mbhh[2*D_+d]));
            float nm = (1.f-zz)*nn + zz*s_mf[d];
            s_mf[d] = nm; s_act[d] = fmaxf(nm, 0.f);
        }
        __syncthreads();
    }
    const float dd = (float)(R_ - 2);
    float p = 0.f;
    for (int d=tid; d<D_; d+=256){
        float acc = bme[d];
        for (int k=0;k<D_;k++){
            float mf = s_mf[k];
            acc += mf * Wme[k*D_ + d];
            acc += (mf + dd) * Wme[(D_+k)*D_ + d];
        }
        p += acc * Wout[d];
    }
    float o = blockReduceSum(p, s_red);
    if (tid==0){
        o += bout[0];
        if (*amtag == FP32TAG) ((float*)out)[b] = o;
        else ((bf16*)out)[b] = __float2bfloat16(o);
    }
}

extern "C" void kernel_launch(void* const* d_in, const int* in_sizes, int n_in,
                              void* d_out, int out_size, void* d_ws, size_t ws_size,
                              hipStream_t stream) {
    const int* adl = (const int*)d_in[2];
    const int* bdl = (const int*)d_in[3];
    const unsigned* amtag = (const unsigned*)d_in[4];

    static const int srcidx[NSEG] = {0,1,4,5,6,7,8,9,10,11,12,15,16,17,18,19,20,21,22,23,24,25,26,27,28};
    static const int segsz[NSEG]  = {638976,327680,16384,7800,200,9800,200,1200,3,120000,600,
                                     1800,1800,400,1,40000,200,120000,120000,600,600,80000,200,200,1};
    CvtArgs ca;
    int ofs[NSEG+1]; ofs[0] = 0;
    for (int i=0;i<NSEG;i++){ ca.src[i] = d_in[srcidx[i]]; ca.ofs[i] = ofs[i]; ofs[i+1] = ofs[i] + segsz[i]; }
    ca.ofs[NSEG] = ofs[NSEG];
    const int total = ofs[NSEG];           // 1488645

    // ws layout (floats; offsets 16B aligned). ~76.5 MB total.
    float* ws   = (float*)d_ws;
    float* conv = ws;                                   // 1488648 (padded)
    float* h    = conv + 1488648;                       // BLD_
    float* cur  = h + BLD_;                             // BLD_
    unsigned short* XH  = (unsigned short*)(cur + BLD_);        // BL_*KP shorts
    unsigned short* B2t = XH + (size_t)BL_*KP;                  // R_*NP*KP shorts
    float* creg = (float*)(B2t + (size_t)R_*NP*KP);             // C region: BL_*NP shorts
    unsigned short* C = (unsigned short*)creg;
    float* wnei = creg;                                 // overlays C
    float* P    = creg + BLD_;                          // overlays C tail (round-0 only)
    float* s1   = creg + (size_t)BL_*NP/2;              // after C region
    float* tb   = s1 + BL_;
    float* wsum = tb + BL_;
    float* mTi  = wsum + BL_;                           // D_*G3D_ = 120000
    float* mTh  = mTi + D_*G3D_;
    float* curdot = mTh + D_*G3D_;                      // BL_

    const float* c_atom  = conv + ofs[0];
    const float* c_bond  = conv + ofs[1];
    const float* c_amask = conv + ofs[2];
    const float* c_Watom = conv + ofs[3];
    const float* c_batom = conv + ofs[4];
    const float* c_Wnei  = conv + ofs[5];
    const float* c_bnei  = conv + ofs[6];
    const float* c_Walign= conv + ofs[7];
    const float* c_balign= conv + ofs[8];
    const float* c_Watt  = conv + ofs[9];
    const float* c_batt  = conv + ofs[10];
    const float* c_bih   = conv + ofs[11];
    const float* c_bhh   = conv + ofs[12];
    const float* c_Wma   = conv + ofs[13];
    const float* c_bma   = conv + ofs[14];
    const float* c_Wmt   = conv + ofs[15];
    const float* c_bmt   = conv + ofs[16];
    const float* c_mWih  = conv + ofs[17];
    const float* c_mWhh  = conv + ofs[18];
    const float* c_mbih  = conv + ofs[19];
    const float* c_mbhh  = conv + ofs[20];
    const float* c_Wme   = conv + ofs[21];
    const float* c_bme   = conv + ofs[22];
    const float* c_Wout  = conv + ofs[23];
    const float* c_bout  = conv + ofs[24];

    k_convert<<<(total + 255)/256, 256, 0, stream>>>(ca, conv, amtag, total);
    k_prepB<<<(R_*NP*KP + 255)/256, 256, 0, stream>>>(d_in[13], d_in[14], B2t, amtag);
    k_prepM<<<(D_*G3D_ + 255)/256, 256, 0, stream>>>(c_mWih, c_mWhh, mTi, mTh);
    k_init<<<BLD_/256, 256, 0, stream>>>(c_atom, c_Watom, c_batom, c_Wnei, c_bnei, h, cur, XH, P);

    for (int r=0; r<R_; r++){
        k_dots<<<BL_/4, 256, 0, stream>>>(cur, c_Walign, r, s1, tb);
        k_attn<<<BL_/4, 256, 0, stream>>>(cur, s1, tb, adl, bdl, P, c_bond,
                                          c_Wnei, c_Walign, c_balign, r, wnei, wsum);
        k_ctxgemm<<<BL_/CTXA, 256, 0, stream>>>(wnei, wsum, c_Watt, c_batt, r, XH);
        k_gemm<<<(BL_/64)*(NP/64), 256, 0, stream>>>(XH, B2t, C, r);
        k_gru2<<<BLD_/256, 256, 0, stream>>>(C, h, cur, XH, c_bih, c_bhh, r);
    }

    k_moldot<<<BL_/4, 256, 0, stream>>>(cur, c_Wma, curdot);
    k_mol<<<B_, 256, 0, stream>>>(cur, curdot, c_amask, c_Wma, c_bma, c_Wmt, c_bmt,
                                  mTi, mTh, c_mbih, c_mbhh, c_Wme, c_bme, c_Wout, c_bout,
                                  d_out, amtag);
}